// Round 1
// baseline (413.135 us; speedup 1.0000x reference)
//
#include <hip/hip_runtime.h>

#define T_SEQ 2048
#define D_MODEL 1024
#define NB 4
#define NH 16
#define HD 64

typedef __attribute__((ext_vector_type(8))) __bf16 bf16x8;
typedef __attribute__((ext_vector_type(4))) __bf16 bf16x4;
typedef __attribute__((ext_vector_type(4))) float f32x4;

__device__ __forceinline__ void gload_lds16(const void* g, void* l) {
  __builtin_amdgcn_global_load_lds((const __attribute__((address_space(1))) unsigned int*)g,
                                   (__attribute__((address_space(3))) unsigned int*)l,
                                   16, 0, 0);
}

// ---------------- convert fp32 -> bf16 (vectorized) ----------------
__global__ __launch_bounds__(256) void cvt_bf16_kernel(const float* __restrict__ s,
                                                       __bf16* __restrict__ d, int n) {
  int i = (blockIdx.x * 256 + threadIdx.x) * 8;
  if (i >= n) return;
  float4 a = *(const float4*)(s + i);
  float4 b = *(const float4*)(s + i + 4);
  bf16x8 v;
  v[0] = (__bf16)a.x; v[1] = (__bf16)a.y; v[2] = (__bf16)a.z; v[3] = (__bf16)a.w;
  v[4] = (__bf16)b.x; v[5] = (__bf16)b.y; v[6] = (__bf16)b.z; v[7] = (__bf16)b.w;
  *(bf16x8*)(d + i) = v;
}

// ---------------- transpose + convert: W[K][N] f32 -> Wt[N][K] bf16 ----------------
__global__ __launch_bounds__(256) void transpose_cvt_kernel(const float* __restrict__ W,
                                                            __bf16* __restrict__ Wt,
                                                            int K, int N) {
  __shared__ float t[32][33];
  int tx = threadIdx.x, ty = threadIdx.y;
  int n0 = blockIdx.x * 32, k0 = blockIdx.y * 32;
#pragma unroll
  for (int r = 0; r < 4; ++r)
    t[ty + r * 8][tx] = W[(size_t)(k0 + ty + r * 8) * N + n0 + tx];
  __syncthreads();
#pragma unroll
  for (int r = 0; r < 4; ++r)
    Wt[(size_t)(n0 + ty + r * 8) * K + k0 + tx] = (__bf16)t[tx][ty + r * 8];
}

// ---------------- extract V^T per head: qkv -> Vt[(b,h,dv)][t] bf16 ----------------
__global__ __launch_bounds__(256) void extract_vt_kernel(const __bf16* __restrict__ qkv,
                                                         __bf16* __restrict__ Vt) {
  __shared__ __bf16 t[32][34];
  int tx = threadIdx.x, ty = threadIdx.y;
  int tt = blockIdx.x * 32;   // seq offset
  int dt = blockIdx.y * 32;   // dv offset
  int bh = blockIdx.z;
  int b = bh >> 4, h = bh & 15;
#pragma unroll
  for (int r = 0; r < 4; ++r)
    t[ty + r * 8][tx] = qkv[(size_t)(b * T_SEQ + tt + ty + r * 8) * 3072 + 2048 + h * HD + dt + tx];
  __syncthreads();
#pragma unroll
  for (int r = 0; r < 4; ++r)
    Vt[(size_t)(bh * HD + dt + ty + r * 8) * T_SEQ + tt + tx] = t[tx][ty + r * 8];
}

// ---------------- GEMM: C[M][N] = A[M][K] * Bt[N][K]^T  (bf16 in, OutT out) ----------------
// 128x128 tile, BK=64, 256 threads (4 waves, 2x2), m97 2-phase structure,
// global_load_lds width-16, XOR-swizzled LDS (pre-swizzled global source).
template <typename OutT>
__global__ __launch_bounds__(256) void gemm_bt(const __bf16* __restrict__ A,
                                               const __bf16* __restrict__ Bt,
                                               OutT* __restrict__ C,
                                               int M, int N, int K) {
  __shared__ __bf16 lA[128 * 64];
  __shared__ __bf16 lB[128 * 64];
  int tid = threadIdx.x;
  int lane = tid & 63, w = tid >> 6;
  int wm = w >> 1, wn = w & 1;
  int bn = blockIdx.x, bm = blockIdx.y;
  f32x4 acc[4][4] = {};
  for (int kt = 0; kt < K; kt += 64) {
#pragma unroll
    for (int it = 0; it < 4; ++it) {
      int o = it * 4096 + tid * 16;          // byte offset in 16KB tile
      int row = o >> 7;                      // 128B per row (64 bf16)
      int ss = ((o >> 4) & 7) ^ (row & 7);   // inverse-swizzled source slot
      gload_lds16(A + (size_t)(bm * 128 + row) * K + kt + ss * 8, (char*)lA + o);
      gload_lds16(Bt + (size_t)(bn * 128 + row) * K + kt + ss * 8, (char*)lB + o);
    }
    __syncthreads();
    bf16x8 af[4][2], bfv[4][2];
#pragma unroll
    for (int i = 0; i < 4; ++i)
#pragma unroll
      for (int kk = 0; kk < 2; ++kk) {
        int ra = wm * 64 + i * 16 + (lane & 15);
        int sa = ((lane >> 4) + kk * 4) ^ (ra & 7);
        af[i][kk] = *(const bf16x8*)((const char*)lA + ra * 128 + sa * 16);
        int rb = wn * 64 + i * 16 + (lane & 15);
        int sb = ((lane >> 4) + kk * 4) ^ (rb & 7);
        bfv[i][kk] = *(const bf16x8*)((const char*)lB + rb * 128 + sb * 16);
      }
#pragma unroll
    for (int kk = 0; kk < 2; ++kk)
#pragma unroll
      for (int i = 0; i < 4; ++i)
#pragma unroll
        for (int j = 0; j < 4; ++j)
          acc[i][j] = __builtin_amdgcn_mfma_f32_16x16x32_bf16(af[i][kk], bfv[j][kk], acc[i][j], 0, 0, 0);
    __syncthreads();
  }
#pragma unroll
  for (int i = 0; i < 4; ++i)
#pragma unroll
    for (int j = 0; j < 4; ++j)
#pragma unroll
      for (int r = 0; r < 4; ++r) {
        int row = bm * 128 + wm * 64 + i * 16 + (lane >> 4) * 4 + r;
        int col = bn * 128 + wn * 64 + j * 16 + (lane & 15);
        C[(size_t)row * N + col] = (OutT)acc[i][j][r];
      }
}

// ---------------- causal flash attention ----------------
// block = (qtile of 64 rows, h, b); 4 waves, each wave owns 16 q rows.
// K tile [64 kv][64 d], V^T tile [64 dv][64 kv] staged in swizzled LDS.
__global__ __launch_bounds__(256) void attn_kernel(const __bf16* __restrict__ qkv,
                                                   const __bf16* __restrict__ Vt,
                                                   __bf16* __restrict__ Y) {
  __shared__ __bf16 lK[64 * 64];
  __shared__ __bf16 lV[64 * 64];
  __shared__ __bf16 lP[4][16 * 72];   // per-wave P tile, row stride 72 elems (144B)
  int tid = threadIdx.x, lane = tid & 63, w = tid >> 6;
  int qt = blockIdx.x, h = blockIdx.y, b = blockIdx.z;
  const float SCALE = 0.125f * 1.44269504088896f;  // 1/sqrt(64) * log2(e)

  // Q fragments (A operand): row = lane&15, k = (lane>>4)*8 + j (+32 per kk)
  const __bf16* qp = qkv + (size_t)(b * T_SEQ + qt * 64 + w * 16 + (lane & 15)) * 3072 + h * HD;
  bf16x8 qf[2];
  qf[0] = *(const bf16x8*)(qp + (lane >> 4) * 8);
  qf[1] = *(const bf16x8*)(qp + 32 + (lane >> 4) * 8);

  const f32x4 fzero = {0.f, 0.f, 0.f, 0.f};
  float m[4], lsum[4];
  f32x4 yacc[4];
#pragma unroll
  for (int r = 0; r < 4; ++r) { m[r] = -INFINITY; lsum[r] = 0.f; }
#pragma unroll
  for (int f = 0; f < 4; ++f) yacc[f] = fzero;

  int qrow = qt * 64 + w * 16 + (lane >> 4) * 4;  // softmax rows (C/D layout)

  for (int kvt = 0; kvt <= qt; ++kvt) {
    // stage K and V^T tiles (8KB each -> 2 issues/thread each)
#pragma unroll
    for (int it = 0; it < 2; ++it) {
      int o = it * 4096 + tid * 16;
      int row = o >> 7;
      int ss = ((o >> 4) & 7) ^ (row & 7);
      gload_lds16(qkv + (size_t)(b * T_SEQ + kvt * 64 + row) * 3072 + 1024 + h * HD + ss * 8,
                  (char*)lK + o);
      gload_lds16(Vt + (size_t)((b * NH + h) * HD + row) * T_SEQ + kvt * 64 + ss * 8,
                  (char*)lV + o);
    }
    __syncthreads();

    // S = Q K^T : 4 kv-frags x 2 k-substeps
    f32x4 s[4];
#pragma unroll
    for (int f = 0; f < 4; ++f) s[f] = fzero;
#pragma unroll
    for (int kk = 0; kk < 2; ++kk)
#pragma unroll
      for (int f = 0; f < 4; ++f) {
        int rk = f * 16 + (lane & 15);
        int sk = ((lane >> 4) + kk * 4) ^ (rk & 7);
        bf16x8 kf = *(const bf16x8*)((const char*)lK + rk * 128 + sk * 16);
        s[f] = __builtin_amdgcn_mfma_f32_16x16x32_bf16(qf[kk], kf, s[f], 0, 0, 0);
      }

    // online softmax, per q-row (= per reg r), wave-parallel reduce over 16 lanes
    int kvb = kvt * 64 + (lane & 15);
#pragma unroll
    for (int r = 0; r < 4; ++r) {
      int qr = qrow + r;
      float sv[4];
      float mx = -INFINITY;
#pragma unroll
      for (int f = 0; f < 4; ++f) {
        float v = s[f][r] * SCALE;
        if (kvb + f * 16 > qr) v = -INFINITY;  // causal mask
        sv[f] = v;
        mx = fmaxf(mx, v);
      }
      mx = fmaxf(mx, __shfl_xor(mx, 1, 64));
      mx = fmaxf(mx, __shfl_xor(mx, 2, 64));
      mx = fmaxf(mx, __shfl_xor(mx, 4, 64));
      mx = fmaxf(mx, __shfl_xor(mx, 8, 64));
      float mn = fmaxf(m[r], mx);
      float alpha = exp2f(m[r] - mn);
      m[r] = mn;
      float ps = 0.f;
#pragma unroll
      for (int f = 0; f < 4; ++f) {
        float p = exp2f(sv[f] - mn);
        ps += p;
        lP[w][((lane >> 4) * 4 + r) * 72 + (lane & 15) + f * 16] = (__bf16)p;
      }
      ps += __shfl_xor(ps, 1, 64);
      ps += __shfl_xor(ps, 2, 64);
      ps += __shfl_xor(ps, 4, 64);
      ps += __shfl_xor(ps, 8, 64);
      lsum[r] = lsum[r] * alpha + ps;
#pragma unroll
      for (int f = 0; f < 4; ++f) yacc[f][r] *= alpha;
    }

    // per-wave LDS P transpose -> A-operand layout
    asm volatile("s_waitcnt lgkmcnt(0)" ::: "memory");
#pragma unroll
    for (int kk = 0; kk < 2; ++kk) {
      const char* pb = (const char*)&lP[w][0] + (lane & 15) * 144 + (lane >> 4) * 16 + kk * 64;
      bf16x4 plo = *(const bf16x4*)pb;
      bf16x4 phi = *(const bf16x4*)(pb + 8);
      bf16x8 pa;
#pragma unroll
      for (int j = 0; j < 4; ++j) { pa[j] = plo[j]; pa[j + 4] = phi[j]; }
#pragma unroll
      for (int f = 0; f < 4; ++f) {
        int rv = f * 16 + (lane & 15);
        int sv2 = ((lane >> 4) + kk * 4) ^ (rv & 7);
        bf16x8 vf = *(const bf16x8*)((const char*)lV + rv * 128 + sv2 * 16);
        yacc[f] = __builtin_amdgcn_mfma_f32_16x16x32_bf16(pa, vf, yacc[f], 0, 0, 0);
      }
    }
    __syncthreads();
  }

  // epilogue: y / l, merged-head layout [b][t][h*64+dv] bf16
#pragma unroll
  for (int f = 0; f < 4; ++f)
#pragma unroll
    for (int r = 0; r < 4; ++r) {
      int qr2 = qrow + r;
      Y[(size_t)(b * T_SEQ + qr2) * D_MODEL + h * HD + f * 16 + (lane & 15)] =
          (__bf16)(yacc[f][r] / lsum[r]);
    }
}

// ---------------- launcher ----------------
extern "C" void kernel_launch(void* const* d_in, const int* in_sizes, int n_in,
                              void* d_out, int out_size, void* d_ws, size_t ws_size,
                              hipStream_t stream) {
  const float* x = (const float*)d_in[0];      // [4,2048,1024]
  const float* Wqkv = (const float*)d_in[1];   // [1024,3072]
  const float* Wproj = (const float*)d_in[2];  // [1024,1024]
  float* out = (float*)d_out;                  // [4,2048,1024]
  char* ws = (char*)d_ws;

  __bf16* Xbf     = (__bf16*)(ws);                       // 16.78 MB
  __bf16* Wqkv_t  = (__bf16*)(ws + 16777216);            // 6.29 MB  [3072][1024]
  __bf16* Wproj_t = (__bf16*)(ws + 23068672);            // 2.10 MB  [1024][1024]
  __bf16* QKV     = (__bf16*)(ws + 25165824);            // 50.33 MB [8192][3072]
  __bf16* Vt      = (__bf16*)(ws + 75497472);            // 16.78 MB [(b,h,dv)][2048]
  __bf16* Yb      = (__bf16*)(ws + 92274688);            // 16.78 MB [8192][1024]

  cvt_bf16_kernel<<<4096, 256, 0, stream>>>(x, Xbf, NB * T_SEQ * D_MODEL);
  transpose_cvt_kernel<<<dim3(96, 32), dim3(32, 8), 0, stream>>>(Wqkv, Wqkv_t, 1024, 3072);
  transpose_cvt_kernel<<<dim3(32, 32), dim3(32, 8), 0, stream>>>(Wproj, Wproj_t, 1024, 1024);
  gemm_bt<__bf16><<<dim3(24, 64), 256, 0, stream>>>(Xbf, Wqkv_t, QKV, 8192, 3072, 1024);
  extract_vt_kernel<<<dim3(64, 2, 64), dim3(32, 8), 0, stream>>>(QKV, Vt);
  attn_kernel<<<dim3(32, 16, 4), 256, 0, stream>>>(QKV, Vt, Yb);
  gemm_bt<float><<<dim3(8, 64), 256, 0, stream>>>(Yb, Wproj_t, out, 8192, 1024, 1024);
}

// Round 3
// 351.612 us; speedup vs baseline: 1.1750x; 1.1750x over previous
//
#include <hip/hip_runtime.h>

#define T_SEQ 2048
#define D_MODEL 1024
#define NB 4
#define NH 16
#define HD 64

typedef __attribute__((ext_vector_type(8))) __bf16 bf16x8;
typedef __attribute__((ext_vector_type(4))) __bf16 bf16x4;
typedef __attribute__((ext_vector_type(4))) float f32x4;

__device__ __forceinline__ void gload_lds16(const void* g, void* l) {
  __builtin_amdgcn_global_load_lds((const __attribute__((address_space(1))) unsigned int*)g,
                                   (__attribute__((address_space(3))) unsigned int*)l,
                                   16, 0, 0);
}

// ---------------- convert fp32 -> bf16 (vectorized) ----------------
__global__ __launch_bounds__(256) void cvt_bf16_kernel(const float* __restrict__ s,
                                                       __bf16* __restrict__ d, int n) {
  int i = (blockIdx.x * 256 + threadIdx.x) * 8;
  if (i >= n) return;
  float4 a = *(const float4*)(s + i);
  float4 b = *(const float4*)(s + i + 4);
  bf16x8 v;
  v[0] = (__bf16)a.x; v[1] = (__bf16)a.y; v[2] = (__bf16)a.z; v[3] = (__bf16)a.w;
  v[4] = (__bf16)b.x; v[5] = (__bf16)b.y; v[6] = (__bf16)b.z; v[7] = (__bf16)b.w;
  *(bf16x8*)(d + i) = v;
}

// ---------------- transpose + convert: W[K][N] f32 -> Wt[N][K] bf16 ----------------
__global__ __launch_bounds__(256) void transpose_cvt_kernel(const float* __restrict__ W,
                                                            __bf16* __restrict__ Wt,
                                                            int K, int N) {
  __shared__ float t[32][33];
  int tx = threadIdx.x, ty = threadIdx.y;
  int n0 = blockIdx.x * 32, k0 = blockIdx.y * 32;
#pragma unroll
  for (int r = 0; r < 4; ++r)
    t[ty + r * 8][tx] = W[(size_t)(k0 + ty + r * 8) * N + n0 + tx];
  __syncthreads();
#pragma unroll
  for (int r = 0; r < 4; ++r)
    Wt[(size_t)(n0 + ty + r * 8) * K + k0 + tx] = (__bf16)t[tx][ty + r * 8];
}

// ---------------- extract V^T per head: qkv -> Vt[(b,h,dv)][t] bf16 ----------------
__global__ __launch_bounds__(256) void extract_vt_kernel(const __bf16* __restrict__ qkv,
                                                         __bf16* __restrict__ Vt) {
  __shared__ __bf16 t[32][34];
  int tx = threadIdx.x, ty = threadIdx.y;
  int tt = blockIdx.x * 32;   // seq offset
  int dt = blockIdx.y * 32;   // dv offset
  int bh = blockIdx.z;
  int b = bh >> 4, h = bh & 15;
#pragma unroll
  for (int r = 0; r < 4; ++r)
    t[ty + r * 8][tx] = qkv[(size_t)(b * T_SEQ + tt + ty + r * 8) * 3072 + 2048 + h * HD + dt + tx];
  __syncthreads();
#pragma unroll
  for (int r = 0; r < 4; ++r)
    Vt[(size_t)(bh * HD + dt + ty + r * 8) * T_SEQ + tt + tx] = t[tx][ty + r * 8];
}

// ---------------- GEMM: C[M][N] = A[M][K] * Bt[N][K]^T  (bf16 in, OutT out) ----------------
template <typename OutT>
__global__ __launch_bounds__(256) void gemm_bt(const __bf16* __restrict__ A,
                                               const __bf16* __restrict__ Bt,
                                               OutT* __restrict__ C,
                                               int M, int N, int K) {
  __shared__ __bf16 lA[128 * 64];
  __shared__ __bf16 lB[128 * 64];
  int tid = threadIdx.x;
  int lane = tid & 63, w = tid >> 6;
  int wm = w >> 1, wn = w & 1;
  int bn = blockIdx.x, bm = blockIdx.y;
  f32x4 acc[4][4] = {};
  for (int kt = 0; kt < K; kt += 64) {
#pragma unroll
    for (int it = 0; it < 4; ++it) {
      int o = it * 4096 + tid * 16;          // byte offset in 16KB tile
      int row = o >> 7;                      // 128B per row (64 bf16)
      int ss = ((o >> 4) & 7) ^ (row & 7);   // inverse-swizzled source slot
      gload_lds16(A + (size_t)(bm * 128 + row) * K + kt + ss * 8, (char*)lA + o);
      gload_lds16(Bt + (size_t)(bn * 128 + row) * K + kt + ss * 8, (char*)lB + o);
    }
    __syncthreads();
    bf16x8 af[4][2], bfv[4][2];
#pragma unroll
    for (int i = 0; i < 4; ++i)
#pragma unroll
      for (int kk = 0; kk < 2; ++kk) {
        int ra = wm * 64 + i * 16 + (lane & 15);
        int sa = ((lane >> 4) + kk * 4) ^ (ra & 7);
        af[i][kk] = *(const bf16x8*)((const char*)lA + ra * 128 + sa * 16);
        int rb = wn * 64 + i * 16 + (lane & 15);
        int sb = ((lane >> 4) + kk * 4) ^ (rb & 7);
        bfv[i][kk] = *(const bf16x8*)((const char*)lB + rb * 128 + sb * 16);
      }
#pragma unroll
    for (int kk = 0; kk < 2; ++kk)
#pragma unroll
      for (int i = 0; i < 4; ++i)
#pragma unroll
        for (int j = 0; j < 4; ++j)
          acc[i][j] = __builtin_amdgcn_mfma_f32_16x16x32_bf16(af[i][kk], bfv[j][kk], acc[i][j], 0, 0, 0);
    __syncthreads();
  }
#pragma unroll
  for (int i = 0; i < 4; ++i)
#pragma unroll
    for (int j = 0; j < 4; ++j)
#pragma unroll
      for (int r = 0; r < 4; ++r) {
        int row = bm * 128 + wm * 64 + i * 16 + (lane >> 4) * 4 + r;
        int col = bn * 128 + wn * 64 + j * 16 + (lane & 15);
        C[(size_t)row * N + col] = (OutT)acc[i][j][r];
      }
}

// ---------------- causal flash attention v2 ----------------
// Paired q-tiles {31-p, p}: every block does exactly 33 kv-tiles (no tail).
// Double-buffered K/V LDS, counted vmcnt (never drain to 0 mid-loop).
// P tile per-wave, 128B rows, XOR-swizzled at 16B-chunk granularity.
// LDS = 2*8K(K) + 2*8K(V) + 4*2K(P) = 40960B -> 4 blocks/CU.
__global__ __launch_bounds__(256) void attn_kernel(const __bf16* __restrict__ qkv,
                                                   const __bf16* __restrict__ Vt,
                                                   __bf16* __restrict__ Y) {
  __shared__ __bf16 lK[2][64 * 64];
  __shared__ __bf16 lV[2][64 * 64];
  __shared__ __bf16 lP[4][16 * 64];
  int tid = threadIdx.x, lane = tid & 63, w = tid >> 6;
  int p = blockIdx.x, h = blockIdx.y, b = blockIdx.z;
  const float SCALE = 0.125f * 1.44269504088896f;  // 1/sqrt(64) * log2(e)

  const f32x4 fzero = {0.f, 0.f, 0.f, 0.f};

#pragma unroll 1
  for (int pass = 0; pass < 2; ++pass) {
    int qt = pass ? p : 31 - p;

    // Q fragments (A operand), prescaled by SCALE
    const __bf16* qp = qkv + (size_t)(b * T_SEQ + qt * 64 + w * 16 + (lane & 15)) * 3072 + h * HD;
    bf16x8 qf[2];
    qf[0] = *(const bf16x8*)(qp + (lane >> 4) * 8);
    qf[1] = *(const bf16x8*)(qp + 32 + (lane >> 4) * 8);
#pragma unroll
    for (int kk = 0; kk < 2; ++kk)
#pragma unroll
      for (int j = 0; j < 8; ++j) qf[kk][j] = (__bf16)((float)qf[kk][j] * SCALE);

    float m[4], lsum[4];
    f32x4 yacc[4];
#pragma unroll
    for (int r = 0; r < 4; ++r) { m[r] = -INFINITY; lsum[r] = 0.f; }
#pragma unroll
    for (int f = 0; f < 4; ++f) yacc[f] = fzero;

    // drain Q loads (and pass-0 Y stores) so vmcnt accounting below is exact
    asm volatile("s_waitcnt vmcnt(0)" ::: "memory");
    __builtin_amdgcn_sched_barrier(0);

    // stage tile kvt into buffer bi (4 gload_lds per thread)
    auto STAGE = [&](int kvt, int bi) {
#pragma unroll
      for (int it = 0; it < 2; ++it) {
        int o = it * 4096 + tid * 16;
        int row = o >> 7;
        int ss = ((o >> 4) & 7) ^ (row & 7);
        gload_lds16(qkv + (size_t)(b * T_SEQ + kvt * 64 + row) * 3072 + 1024 + h * HD + ss * 8,
                    (char*)lK[bi] + o);
        gload_lds16(Vt + (size_t)((b * NH + h) * HD + row) * T_SEQ + kvt * 64 + ss * 8,
                    (char*)lV[bi] + o);
      }
    };

    STAGE(0, 0);

#pragma unroll 1
    for (int kvt = 0; kvt <= qt; ++kvt) {
      int cur = kvt & 1;
      bool pf = (kvt < qt);
      if (pf) {
        STAGE(kvt + 1, cur ^ 1);
        asm volatile("s_waitcnt vmcnt(4)" ::: "memory");  // cur tile landed; prefetch in flight
      } else {
        asm volatile("s_waitcnt vmcnt(0)" ::: "memory");
      }
      __builtin_amdgcn_sched_barrier(0);
      __builtin_amdgcn_s_barrier();
      __builtin_amdgcn_sched_barrier(0);

      // ---- S = Q K^T ----
      f32x4 s[4];
#pragma unroll
      for (int f = 0; f < 4; ++f) s[f] = fzero;
      const char* Kbase = (const char*)lK[cur];
      __builtin_amdgcn_s_setprio(1);
#pragma unroll
      for (int kk = 0; kk < 2; ++kk)
#pragma unroll
        for (int f = 0; f < 4; ++f) {
          int rk = f * 16 + (lane & 15);
          int sk = ((lane >> 4) + kk * 4) ^ (rk & 7);
          bf16x8 kf = *(const bf16x8*)(Kbase + rk * 128 + sk * 16);
          s[f] = __builtin_amdgcn_mfma_f32_16x16x32_bf16(qf[kk], kf, s[f], 0, 0, 0);
        }
      __builtin_amdgcn_s_setprio(0);

      // ---- online softmax (mask only on diagonal tile; deferred lsum reduce) ----
      bool diag = (kvt == qt);
#pragma unroll
      for (int r = 0; r < 4; ++r) {
        int qw = (lane >> 4) * 4 + r;        // wave-local q row 0..15
        int qloc = w * 16 + qw;              // block-local q row 0..63
        float sv[4];
        if (diag) {
          int kvb = lane & 15;
#pragma unroll
          for (int f = 0; f < 4; ++f) {
            float v = s[f][r];
            if (kvb + f * 16 > qloc) v = -INFINITY;
            sv[f] = v;
          }
        } else {
#pragma unroll
          for (int f = 0; f < 4; ++f) sv[f] = s[f][r];
        }
        float mx = fmaxf(fmaxf(sv[0], sv[1]), fmaxf(sv[2], sv[3]));
        mx = fmaxf(mx, __shfl_xor(mx, 1, 64));
        mx = fmaxf(mx, __shfl_xor(mx, 2, 64));
        mx = fmaxf(mx, __shfl_xor(mx, 4, 64));
        mx = fmaxf(mx, __shfl_xor(mx, 8, 64));
        if (mx > m[r]) {                      // exact skip-rescale
          float alpha = exp2f(m[r] - mx);
          m[r] = mx;
          lsum[r] *= alpha;
#pragma unroll
          for (int f = 0; f < 4; ++f) yacc[f][r] *= alpha;
        }
        float ps = 0.f;
#pragma unroll
        for (int f = 0; f < 4; ++f) {
          float pe = exp2f(sv[f] - m[r]);
          ps += pe;
          // write P[qw][c], c = (lane&15) + f*16; swizzle 16B chunk idx by qw&7
          int bofs = (((lane & 15) * 2 + f * 32) ^ ((qw & 7) << 4));
          *(__bf16*)((char*)lP[w] + qw * 128 + bofs) = (__bf16)pe;
        }
        lsum[r] += ps;                        // per-lane partial; reduced in epilogue
      }

      // ---- O += P V ----
      asm volatile("s_waitcnt lgkmcnt(0)" ::: "memory");
      __builtin_amdgcn_sched_barrier(0);
      const char* Vbase = (const char*)lV[cur];
      __builtin_amdgcn_s_setprio(1);
#pragma unroll
      for (int kk = 0; kk < 2; ++kk) {
        int q = lane & 15;
        int bofs = (((lane >> 4) * 16 + kk * 64) ^ ((q & 7) << 4));
        bf16x8 pa = *(const bf16x8*)((const char*)lP[w] + q * 128 + bofs);
#pragma unroll
        for (int f = 0; f < 4; ++f) {
          int rv = f * 16 + (lane & 15);
          int sv2 = ((lane >> 4) + kk * 4) ^ (rv & 7);
          bf16x8 vf = *(const bf16x8*)(Vbase + rv * 128 + sv2 * 16);
          yacc[f] = __builtin_amdgcn_mfma_f32_16x16x32_bf16(pa, vf, yacc[f], 0, 0, 0);
        }
      }
      __builtin_amdgcn_s_setprio(0);

      // all waves done reading cur before next iter's STAGE overwrites it
      __builtin_amdgcn_sched_barrier(0);
      asm volatile("s_waitcnt lgkmcnt(0)" ::: "memory");
      __builtin_amdgcn_s_barrier();
      __builtin_amdgcn_sched_barrier(0);
    }

    // ---- epilogue: reduce lsum across the 16 kv-lanes, then y / l ----
    float ltot[4];
#pragma unroll
    for (int r = 0; r < 4; ++r) {
      float ls = lsum[r];
      ls += __shfl_xor(ls, 1, 64);
      ls += __shfl_xor(ls, 2, 64);
      ls += __shfl_xor(ls, 4, 64);
      ls += __shfl_xor(ls, 8, 64);
      ltot[r] = 1.0f / ls;
    }
    int qrow = qt * 64 + w * 16 + (lane >> 4) * 4;
#pragma unroll
    for (int f = 0; f < 4; ++f)
#pragma unroll
      for (int r = 0; r < 4; ++r) {
        Y[(size_t)(b * T_SEQ + qrow + r) * D_MODEL + h * HD + f * 16 + (lane & 15)] =
            (__bf16)(yacc[f][r] * ltot[r]);
      }
  }
}

// ---------------- launcher ----------------
extern "C" void kernel_launch(void* const* d_in, const int* in_sizes, int n_in,
                              void* d_out, int out_size, void* d_ws, size_t ws_size,
                              hipStream_t stream) {
  const float* x = (const float*)d_in[0];      // [4,2048,1024]
  const float* Wqkv = (const float*)d_in[1];   // [1024,3072]
  const float* Wproj = (const float*)d_in[2];  // [1024,1024]
  float* out = (float*)d_out;                  // [4,2048,1024]
  char* ws = (char*)d_ws;

  __bf16* Xbf     = (__bf16*)(ws);                       // 16.78 MB
  __bf16* Wqkv_t  = (__bf16*)(ws + 16777216);            // 6.29 MB  [3072][1024]
  __bf16* Wproj_t = (__bf16*)(ws + 23068672);            // 2.10 MB  [1024][1024]
  __bf16* QKV     = (__bf16*)(ws + 25165824);            // 50.33 MB [8192][3072]
  __bf16* Vt      = (__bf16*)(ws + 75497472);            // 16.78 MB [(b,h,dv)][2048]
  __bf16* Yb      = (__bf16*)(ws + 92274688);            // 16.78 MB [8192][1024]

  cvt_bf16_kernel<<<4096, 256, 0, stream>>>(x, Xbf, NB * T_SEQ * D_MODEL);
  transpose_cvt_kernel<<<dim3(96, 32), dim3(32, 8), 0, stream>>>(Wqkv, Wqkv_t, 1024, 3072);
  transpose_cvt_kernel<<<dim3(32, 32), dim3(32, 8), 0, stream>>>(Wproj, Wproj_t, 1024, 1024);
  gemm_bt<__bf16><<<dim3(24, 64), 256, 0, stream>>>(Xbf, Wqkv_t, QKV, 8192, 3072, 1024);
  extract_vt_kernel<<<dim3(64, 2, 64), dim3(32, 8), 0, stream>>>(QKV, Vt);
  attn_kernel<<<dim3(16, 16, 4), 256, 0, stream>>>(QKV, Vt, Yb);
  gemm_bt<float><<<dim3(8, 64), 256, 0, stream>>>(Yb, Wproj_t, out, 8192, 1024, 1024);
}

// Round 4
// 316.150 us; speedup vs baseline: 1.3068x; 1.1122x over previous
//
#include <hip/hip_runtime.h>

#define T_SEQ 2048
#define D_MODEL 1024
#define NB 4
#define NH 16
#define HD 64

typedef __attribute__((ext_vector_type(8))) __bf16 bf16x8;
typedef __attribute__((ext_vector_type(4))) __bf16 bf16x4;
typedef __attribute__((ext_vector_type(4))) float f32x4;

__device__ __forceinline__ void gload_lds16(const void* g, void* l) {
  __builtin_amdgcn_global_load_lds((const __attribute__((address_space(1))) unsigned int*)g,
                                   (__attribute__((address_space(3))) unsigned int*)l,
                                   16, 0, 0);
}

__device__ __forceinline__ unsigned int pack_bf16_2(float e0, float e1) {
  unsigned short u0 = __builtin_bit_cast(unsigned short, (__bf16)e0);
  unsigned short u1 = __builtin_bit_cast(unsigned short, (__bf16)e1);
  return (unsigned int)u0 | ((unsigned int)u1 << 16);
}

// ---------------- convert fp32 -> bf16 (vectorized) ----------------
__global__ __launch_bounds__(256) void cvt_bf16_kernel(const float* __restrict__ s,
                                                       __bf16* __restrict__ d, int n) {
  int i = (blockIdx.x * 256 + threadIdx.x) * 8;
  if (i >= n) return;
  float4 a = *(const float4*)(s + i);
  float4 b = *(const float4*)(s + i + 4);
  bf16x8 v;
  v[0] = (__bf16)a.x; v[1] = (__bf16)a.y; v[2] = (__bf16)a.z; v[3] = (__bf16)a.w;
  v[4] = (__bf16)b.x; v[5] = (__bf16)b.y; v[6] = (__bf16)b.z; v[7] = (__bf16)b.w;
  *(bf16x8*)(d + i) = v;
}

// ---------------- transpose + convert: W[K][N] f32 -> Wt[N][K] bf16 ----------------
__global__ __launch_bounds__(256) void transpose_cvt_kernel(const float* __restrict__ W,
                                                            __bf16* __restrict__ Wt,
                                                            int K, int N) {
  __shared__ float t[32][33];
  int tx = threadIdx.x, ty = threadIdx.y;
  int n0 = blockIdx.x * 32, k0 = blockIdx.y * 32;
#pragma unroll
  for (int r = 0; r < 4; ++r)
    t[ty + r * 8][tx] = W[(size_t)(k0 + ty + r * 8) * N + n0 + tx];
  __syncthreads();
#pragma unroll
  for (int r = 0; r < 4; ++r)
    Wt[(size_t)(n0 + ty + r * 8) * K + k0 + tx] = (__bf16)t[tx][ty + r * 8];
}

// ---------------- extract V^T per head: qkv -> Vt[(b,h,dv)][t] bf16 ----------------
__global__ __launch_bounds__(256) void extract_vt_kernel(const __bf16* __restrict__ qkv,
                                                         __bf16* __restrict__ Vt) {
  __shared__ __bf16 t[32][34];
  int tx = threadIdx.x, ty = threadIdx.y;
  int tt = blockIdx.x * 32;   // seq offset
  int dt = blockIdx.y * 32;   // dv offset
  int bh = blockIdx.z;
  int b = bh >> 4, h = bh & 15;
#pragma unroll
  for (int r = 0; r < 4; ++r)
    t[ty + r * 8][tx] = qkv[(size_t)(b * T_SEQ + tt + ty + r * 8) * 3072 + 2048 + h * HD + dt + tx];
  __syncthreads();
#pragma unroll
  for (int r = 0; r < 4; ++r)
    Vt[(size_t)(bh * HD + dt + ty + r * 8) * T_SEQ + tt + tx] = t[tx][ty + r * 8];
}

// ---------------- GEMM: C[M][N] = A[M][K] * Bt[N][K]^T  (bf16 in, OutT out) ----------------
template <typename OutT>
__global__ __launch_bounds__(256) void gemm_bt(const __bf16* __restrict__ A,
                                               const __bf16* __restrict__ Bt,
                                               OutT* __restrict__ C,
                                               int M, int N, int K) {
  __shared__ __bf16 lA[128 * 64];
  __shared__ __bf16 lB[128 * 64];
  int tid = threadIdx.x;
  int lane = tid & 63, w = tid >> 6;
  int wm = w >> 1, wn = w & 1;
  int bn = blockIdx.x, bm = blockIdx.y;
  f32x4 acc[4][4] = {};
  for (int kt = 0; kt < K; kt += 64) {
#pragma unroll
    for (int it = 0; it < 4; ++it) {
      int o = it * 4096 + tid * 16;          // byte offset in 16KB tile
      int row = o >> 7;                      // 128B per row (64 bf16)
      int ss = ((o >> 4) & 7) ^ (row & 7);   // inverse-swizzled source slot
      gload_lds16(A + (size_t)(bm * 128 + row) * K + kt + ss * 8, (char*)lA + o);
      gload_lds16(Bt + (size_t)(bn * 128 + row) * K + kt + ss * 8, (char*)lB + o);
    }
    __syncthreads();
    bf16x8 af[4][2], bfv[4][2];
#pragma unroll
    for (int i = 0; i < 4; ++i)
#pragma unroll
      for (int kk = 0; kk < 2; ++kk) {
        int ra = wm * 64 + i * 16 + (lane & 15);
        int sa = ((lane >> 4) + kk * 4) ^ (ra & 7);
        af[i][kk] = *(const bf16x8*)((const char*)lA + ra * 128 + sa * 16);
        int rb = wn * 64 + i * 16 + (lane & 15);
        int sb = ((lane >> 4) + kk * 4) ^ (rb & 7);
        bfv[i][kk] = *(const bf16x8*)((const char*)lB + rb * 128 + sb * 16);
      }
#pragma unroll
    for (int kk = 0; kk < 2; ++kk)
#pragma unroll
      for (int i = 0; i < 4; ++i)
#pragma unroll
        for (int j = 0; j < 4; ++j)
          acc[i][j] = __builtin_amdgcn_mfma_f32_16x16x32_bf16(af[i][kk], bfv[j][kk], acc[i][j], 0, 0, 0);
    __syncthreads();
  }
#pragma unroll
  for (int i = 0; i < 4; ++i)
#pragma unroll
    for (int j = 0; j < 4; ++j)
#pragma unroll
      for (int r = 0; r < 4; ++r) {
        int row = bm * 128 + wm * 64 + i * 16 + (lane >> 4) * 4 + r;
        int col = bn * 128 + wn * 64 + j * 16 + (lane & 15);
        C[(size_t)row * N + col] = (OutT)acc[i][j][r];
      }
}

// ---------------- causal flash attention v3: swapped-QK in-register softmax ----------------
// S^T = mfma(K, Q): lane owns q = lane&15, kv = f*16 + g*4 + r (g = lane>>4).
// Row-max: 16 local fmax + 2 shfl. P packed to bf16 in-reg, redistributed to
// PV A-operand layout by 16 shfl + 8 selects (no P LDS round trip).
// Paired q-tiles {31-p, p}: every block = 33 kv tiles. Double-buffered K/V,
// counted vmcnt. LDS = 32KB. XCD-decode: 8 (h,b) pairs per XCD (K/V L2-local).
__global__ __launch_bounds__(256) void attn_kernel(const __bf16* __restrict__ qkv,
                                                   const __bf16* __restrict__ Vt,
                                                   __bf16* __restrict__ Y) {
  __shared__ __bf16 lK[2][64 * 64];
  __shared__ __bf16 lV[2][64 * 64];
  int tid = threadIdx.x, lane = tid & 63, w = tid >> 6;
  int q = lane & 15, g = lane >> 4;

  // XCD-aware decode: linear id l -> (p, h, b) with all 16 p of one (h,b) on one XCD
  int l = blockIdx.x;
  int j0 = l >> 3;
  int pair = ((l & 7) << 3) | (j0 >> 4);
  int p = j0 & 15;
  int h = pair & 15;
  int b = pair >> 4;

  const float SCALE = 0.125f * 1.44269504088896f;  // 1/sqrt(64) * log2(e)
  const f32x4 fzero = {0.f, 0.f, 0.f, 0.f};

#pragma unroll 1
  for (int pass = 0; pass < 2; ++pass) {
    int qt = pass ? p : 31 - p;

    // Q fragments (B operand for swapped QK; same register layout as A), prescaled
    const __bf16* qp = qkv + (size_t)(b * T_SEQ + qt * 64 + w * 16 + q) * 3072 + h * HD;
    bf16x8 qf[2];
    qf[0] = *(const bf16x8*)(qp + g * 8);
    qf[1] = *(const bf16x8*)(qp + 32 + g * 8);
#pragma unroll
    for (int kk = 0; kk < 2; ++kk)
#pragma unroll
      for (int jj = 0; jj < 8; ++jj) qf[kk][jj] = (__bf16)((float)qf[kk][jj] * SCALE);

    float m = -INFINITY, lsum = 0.f;
    f32x4 yacc[4];
#pragma unroll
    for (int f = 0; f < 4; ++f) yacc[f] = fzero;

    // drain Q loads / prior-pass stores so vmcnt accounting is exact
    asm volatile("s_waitcnt vmcnt(0)" ::: "memory");
    __builtin_amdgcn_sched_barrier(0);

    auto STAGE = [&](int kvt, int bi) {
#pragma unroll
      for (int it = 0; it < 2; ++it) {
        int o = it * 4096 + tid * 16;
        int row = o >> 7;
        int ss = ((o >> 4) & 7) ^ (row & 7);
        gload_lds16(qkv + (size_t)(b * T_SEQ + kvt * 64 + row) * 3072 + 1024 + h * HD + ss * 8,
                    (char*)lK[bi] + o);
        gload_lds16(Vt + (size_t)((b * NH + h) * HD + row) * T_SEQ + kvt * 64 + ss * 8,
                    (char*)lV[bi] + o);
      }
    };

    STAGE(0, 0);

#pragma unroll 1
    for (int kvt = 0; kvt <= qt; ++kvt) {
      int cur = kvt & 1;
      if (kvt < qt) {
        STAGE(kvt + 1, cur ^ 1);
        asm volatile("s_waitcnt vmcnt(4)" ::: "memory");  // cur landed; prefetch in flight
      } else {
        asm volatile("s_waitcnt vmcnt(0)" ::: "memory");
      }
      __builtin_amdgcn_sched_barrier(0);
      __builtin_amdgcn_s_barrier();
      __builtin_amdgcn_sched_barrier(0);

      // ---- S^T = K Q^T : s[f][r] = S[q][kv = f*16 + g*4 + r] ----
      f32x4 s[4];
#pragma unroll
      for (int f = 0; f < 4; ++f) s[f] = fzero;
      const char* Kbase = (const char*)lK[cur];
      __builtin_amdgcn_s_setprio(1);
#pragma unroll
      for (int kk = 0; kk < 2; ++kk)
#pragma unroll
        for (int f = 0; f < 4; ++f) {
          int rk = f * 16 + q;
          int sk = (g + kk * 4) ^ (rk & 7);
          bf16x8 kf = *(const bf16x8*)(Kbase + rk * 128 + sk * 16);
          s[f] = __builtin_amdgcn_mfma_f32_16x16x32_bf16(kf, qf[kk], s[f], 0, 0, 0);
        }
      __builtin_amdgcn_s_setprio(0);

      // ---- in-register online softmax ----
      if (kvt == qt) {  // causal mask (diagonal tile only)
        int qloc = w * 16 + q;
#pragma unroll
        for (int f = 0; f < 4; ++f)
#pragma unroll
          for (int r = 0; r < 4; ++r)
            if (f * 16 + g * 4 + r > qloc) s[f][r] = -INFINITY;
      }
      float mx = fmaxf(fmaxf(fmaxf(s[0][0], s[0][1]), fmaxf(s[0][2], s[0][3])),
                       fmaxf(fmaxf(s[1][0], s[1][1]), fmaxf(s[1][2], s[1][3])));
      mx = fmaxf(mx, fmaxf(fmaxf(fmaxf(s[2][0], s[2][1]), fmaxf(s[2][2], s[2][3])),
                           fmaxf(fmaxf(s[3][0], s[3][1]), fmaxf(s[3][2], s[3][3]))));
      mx = fmaxf(mx, __shfl_xor(mx, 16, 64));
      mx = fmaxf(mx, __shfl_xor(mx, 32, 64));
      bool grew = mx > m;
      float alpha = 1.0f;
      if (grew) {
        alpha = exp2f(m - mx);
        m = mx;
        lsum *= alpha;
      }
      if (__any(grew)) {  // rescale O rows (q' = g*4 + r); alpha uniform across g per q
#pragma unroll
        for (int r = 0; r < 4; ++r) {
          float ar = __shfl(alpha, g * 4 + r, 64);
#pragma unroll
          for (int f = 0; f < 4; ++f) yacc[f][r] *= ar;
        }
      }
      // P = exp2(S - m), pack pairs (r=2h, 2h+1) per kv-block
      float ps = 0.f;
      unsigned int W[4][2];
#pragma unroll
      for (int f = 0; f < 4; ++f)
#pragma unroll
        for (int hh = 0; hh < 2; ++hh) {
          float e0 = exp2f(s[f][2 * hh] - m);
          float e1 = exp2f(s[f][2 * hh + 1] - m);
          ps += e0 + e1;
          W[f][hh] = pack_bf16_2(e0, e1);
        }
      lsum += ps;

      // redistribute P words to PV A-operand frags:
      // pa[kk] word t = W[2kk + (g>>1)][t&1] from lane (2(g&1) + (t>>1))*16 + q
      int srcA = ((g & 1) << 5) | q;
      int srcB = srcA + 16;
      bool hisel = (g >= 2);
      bf16x8 pa[2];
#pragma unroll
      for (int kk = 0; kk < 2; ++kk) {
        unsigned int pw[4];
#pragma unroll
        for (int t = 0; t < 4; ++t) {
          int src = (t < 2) ? srcA : srcB;
          unsigned int c0 = (unsigned int)__shfl((int)W[2 * kk][t & 1], src, 64);
          unsigned int c1 = (unsigned int)__shfl((int)W[2 * kk + 1][t & 1], src, 64);
          pw[t] = hisel ? c1 : c0;
        }
        uint4 u = make_uint4(pw[0], pw[1], pw[2], pw[3]);
        pa[kk] = __builtin_bit_cast(bf16x8, u);
      }

      // ---- O += P V ----
      const char* Vbase = (const char*)lV[cur];
      __builtin_amdgcn_s_setprio(1);
#pragma unroll
      for (int kk = 0; kk < 2; ++kk)
#pragma unroll
        for (int f = 0; f < 4; ++f) {
          int rv = f * 16 + q;
          int sv2 = (g + kk * 4) ^ (rv & 7);
          bf16x8 vf = *(const bf16x8*)(Vbase + rv * 128 + sv2 * 16);
          yacc[f] = __builtin_amdgcn_mfma_f32_16x16x32_bf16(pa[kk], vf, yacc[f], 0, 0, 0);
        }
      __builtin_amdgcn_s_setprio(0);

      // all waves done reading cur before next iter's STAGE overwrites the other buffer
      __builtin_amdgcn_sched_barrier(0);
      asm volatile("s_waitcnt lgkmcnt(0)" ::: "memory");
      __builtin_amdgcn_s_barrier();
      __builtin_amdgcn_sched_barrier(0);
    }

    // ---- epilogue: reduce lsum over g-groups, redistribute to O rows, store ----
    float ls = lsum;
    ls += __shfl_xor(ls, 16, 64);
    ls += __shfl_xor(ls, 32, 64);
    float linv = 1.0f / ls;
    int qrow = qt * 64 + w * 16 + g * 4;
#pragma unroll
    for (int r = 0; r < 4; ++r) {
      float lr = __shfl(linv, g * 4 + r, 64);
#pragma unroll
      for (int f = 0; f < 4; ++f) {
        Y[(size_t)(b * T_SEQ + qrow + r) * D_MODEL + h * HD + f * 16 + q] =
            (__bf16)(yacc[f][r] * lr);
      }
    }
  }
}

// ---------------- launcher ----------------
extern "C" void kernel_launch(void* const* d_in, const int* in_sizes, int n_in,
                              void* d_out, int out_size, void* d_ws, size_t ws_size,
                              hipStream_t stream) {
  const float* x = (const float*)d_in[0];      // [4,2048,1024]
  const float* Wqkv = (const float*)d_in[1];   // [1024,3072]
  const float* Wproj = (const float*)d_in[2];  // [1024,1024]
  float* out = (float*)d_out;                  // [4,2048,1024]
  char* ws = (char*)d_ws;

  __bf16* Xbf     = (__bf16*)(ws);                       // 16.78 MB
  __bf16* Wqkv_t  = (__bf16*)(ws + 16777216);            // 6.29 MB  [3072][1024]
  __bf16* Wproj_t = (__bf16*)(ws + 23068672);            // 2.10 MB  [1024][1024]
  __bf16* QKV     = (__bf16*)(ws + 25165824);            // 50.33 MB [8192][3072]
  __bf16* Vt      = (__bf16*)(ws + 75497472);            // 16.78 MB [(b,h,dv)][2048]
  __bf16* Yb      = (__bf16*)(ws + 92274688);            // 16.78 MB [8192][1024]

  cvt_bf16_kernel<<<4096, 256, 0, stream>>>(x, Xbf, NB * T_SEQ * D_MODEL);
  transpose_cvt_kernel<<<dim3(96, 32), dim3(32, 8), 0, stream>>>(Wqkv, Wqkv_t, 1024, 3072);
  transpose_cvt_kernel<<<dim3(32, 32), dim3(32, 8), 0, stream>>>(Wproj, Wproj_t, 1024, 1024);
  gemm_bt<__bf16><<<dim3(24, 64), 256, 0, stream>>>(Xbf, Wqkv_t, QKV, 8192, 3072, 1024);
  extract_vt_kernel<<<dim3(64, 2, 64), dim3(32, 8), 0, stream>>>(QKV, Vt);
  attn_kernel<<<1024, 256, 0, stream>>>(QKV, Vt, Yb);
  gemm_bt<float><<<dim3(8, 64), 256, 0, stream>>>(Yb, Wproj_t, out, 8192, 1024, 1024);
}

// Round 5
// 299.677 us; speedup vs baseline: 1.3786x; 1.0550x over previous
//
#include <hip/hip_runtime.h>

#define T_SEQ 2048
#define D_MODEL 1024
#define NB 4
#define NH 16
#define HD 64

typedef __attribute__((ext_vector_type(8))) __bf16 bf16x8;
typedef __attribute__((ext_vector_type(4))) __bf16 bf16x4;
typedef __attribute__((ext_vector_type(4))) float f32x4;

__device__ __forceinline__ void gload_lds16(const void* g, void* l) {
  __builtin_amdgcn_global_load_lds((const __attribute__((address_space(1))) unsigned int*)g,
                                   (__attribute__((address_space(3))) unsigned int*)l,
                                   16, 0, 0);
}

__device__ __forceinline__ unsigned int pack_bf16_2(float e0, float e1) {
  unsigned short u0 = __builtin_bit_cast(unsigned short, (__bf16)e0);
  unsigned short u1 = __builtin_bit_cast(unsigned short, (__bf16)e1);
  return (unsigned int)u0 | ((unsigned int)u1 << 16);
}

// ---------------- convert fp32 -> bf16 (vectorized) ----------------
__global__ __launch_bounds__(256) void cvt_bf16_kernel(const float* __restrict__ s,
                                                       __bf16* __restrict__ d, int n) {
  int i = (blockIdx.x * 256 + threadIdx.x) * 8;
  if (i >= n) return;
  float4 a = *(const float4*)(s + i);
  float4 b = *(const float4*)(s + i + 4);
  bf16x8 v;
  v[0] = (__bf16)a.x; v[1] = (__bf16)a.y; v[2] = (__bf16)a.z; v[3] = (__bf16)a.w;
  v[4] = (__bf16)b.x; v[5] = (__bf16)b.y; v[6] = (__bf16)b.z; v[7] = (__bf16)b.w;
  *(bf16x8*)(d + i) = v;
}

// ---------------- transpose + convert: W[K][N] f32 -> Wt[N][K] bf16 ----------------
__global__ __launch_bounds__(256) void transpose_cvt_kernel(const float* __restrict__ W,
                                                            __bf16* __restrict__ Wt,
                                                            int K, int N) {
  __shared__ float t[32][33];
  int tx = threadIdx.x, ty = threadIdx.y;
  int n0 = blockIdx.x * 32, k0 = blockIdx.y * 32;
#pragma unroll
  for (int r = 0; r < 4; ++r)
    t[ty + r * 8][tx] = W[(size_t)(k0 + ty + r * 8) * N + n0 + tx];
  __syncthreads();
#pragma unroll
  for (int r = 0; r < 4; ++r)
    Wt[(size_t)(n0 + ty + r * 8) * K + k0 + tx] = (__bf16)t[tx][ty + r * 8];
}

// ---------------- extract V^T per head: qkv -> Vt[(b,h,dv)][t] bf16 ----------------
__global__ __launch_bounds__(256) void extract_vt_kernel(const __bf16* __restrict__ qkv,
                                                         __bf16* __restrict__ Vt) {
  __shared__ __bf16 t[32][34];
  int tx = threadIdx.x, ty = threadIdx.y;
  int tt = blockIdx.x * 32;   // seq offset
  int dt = blockIdx.y * 32;   // dv offset
  int bh = blockIdx.z;
  int b = bh >> 4, h = bh & 15;
#pragma unroll
  for (int r = 0; r < 4; ++r)
    t[ty + r * 8][tx] = qkv[(size_t)(b * T_SEQ + tt + ty + r * 8) * 3072 + 2048 + h * HD + dt + tx];
  __syncthreads();
#pragma unroll
  for (int r = 0; r < 4; ++r)
    Vt[(size_t)(bh * HD + dt + ty + r * 8) * T_SEQ + tt + tx] = t[tx][ty + r * 8];
}

// ---------------- GEMM: C[M][N] = A[M][K] * Bt[N][K]^T  (bf16 in, OutT out) ----------------
// 128x128 tile, BK=64, 4 waves, gload_lds width-16, XOR-swizzled LDS,
// bijective XCD-aware block swizzle (requires nwg % 8 == 0).
template <typename OutT>
__global__ __launch_bounds__(256) void gemm_bt(const __bf16* __restrict__ A,
                                               const __bf16* __restrict__ Bt,
                                               OutT* __restrict__ C,
                                               int M, int N, int K) {
  __shared__ __bf16 lA[128 * 64];
  __shared__ __bf16 lB[128 * 64];
  int tid = threadIdx.x;
  int lane = tid & 63, w = tid >> 6;
  int wm = w >> 1, wn = w & 1;
  // XCD swizzle: each XCD gets a contiguous swz range -> contiguous bm rows
  int nwgx = gridDim.x;
  int lid = blockIdx.y * nwgx + blockIdx.x;
  int cpx = (nwgx * gridDim.y) >> 3;
  int swz = (lid & 7) * cpx + (lid >> 3);
  int bn = swz % nwgx, bm = swz / nwgx;
  f32x4 acc[4][4] = {};
  for (int kt = 0; kt < K; kt += 64) {
#pragma unroll
    for (int it = 0; it < 4; ++it) {
      int o = it * 4096 + tid * 16;          // byte offset in 16KB tile
      int row = o >> 7;                      // 128B per row (64 bf16)
      int ss = ((o >> 4) & 7) ^ (row & 7);   // inverse-swizzled source slot
      gload_lds16(A + (size_t)(bm * 128 + row) * K + kt + ss * 8, (char*)lA + o);
      gload_lds16(Bt + (size_t)(bn * 128 + row) * K + kt + ss * 8, (char*)lB + o);
    }
    __syncthreads();
    bf16x8 af[4][2], bfv[4][2];
#pragma unroll
    for (int i = 0; i < 4; ++i)
#pragma unroll
      for (int kk = 0; kk < 2; ++kk) {
        int ra = wm * 64 + i * 16 + (lane & 15);
        int sa = ((lane >> 4) + kk * 4) ^ (ra & 7);
        af[i][kk] = *(const bf16x8*)((const char*)lA + ra * 128 + sa * 16);
        int rb = wn * 64 + i * 16 + (lane & 15);
        int sb = ((lane >> 4) + kk * 4) ^ (rb & 7);
        bfv[i][kk] = *(const bf16x8*)((const char*)lB + rb * 128 + sb * 16);
      }
#pragma unroll
    for (int kk = 0; kk < 2; ++kk)
#pragma unroll
      for (int i = 0; i < 4; ++i)
#pragma unroll
        for (int j = 0; j < 4; ++j)
          acc[i][j] = __builtin_amdgcn_mfma_f32_16x16x32_bf16(af[i][kk], bfv[j][kk], acc[i][j], 0, 0, 0);
    __syncthreads();
  }
#pragma unroll
  for (int i = 0; i < 4; ++i)
#pragma unroll
    for (int j = 0; j < 4; ++j)
#pragma unroll
      for (int r = 0; r < 4; ++r) {
        int row = bm * 128 + wm * 64 + i * 16 + (lane >> 4) * 4 + r;
        int col = bn * 128 + wn * 64 + j * 16 + (lane & 15);
        C[(size_t)row * N + col] = (OutT)acc[i][j][r];
      }
}

// ---------------- causal flash attention v4 ----------------
// 2 waves x 32 q-rows (2 A-frags per wave): each K/V frag read feeds 2 MFMAs.
// Swapped-QK in-register softmax per qi; defer-max rescale (THR=8 in exp2 units).
// Paired q-tiles {31-p, p} -> 33 kv tiles/block. Double-buffered K/V, counted
// vmcnt(8). LDS 32KB. XCD decode: all 16 p-blocks of a (h,b) on one XCD.
__global__ __launch_bounds__(128) void attn_kernel(const __bf16* __restrict__ qkv,
                                                   const __bf16* __restrict__ Vt,
                                                   __bf16* __restrict__ Y) {
  __shared__ __bf16 lK[2][64 * 64];
  __shared__ __bf16 lV[2][64 * 64];
  int tid = threadIdx.x, lane = tid & 63, w = tid >> 6;  // w in {0,1}
  int q = lane & 15, g = lane >> 4;

  // XCD-aware decode: l -> (p, h, b), 16 p-blocks of one (h,b) per XCD slice
  int l = blockIdx.x;
  int pairHB = ((l & 7) << 3) | (l >> 7);
  int p = (l >> 3) & 15;
  int h = pairHB & 15, b = pairHB >> 4;

  const float SCALE = 0.125f * 1.44269504088896f;  // 1/sqrt(64) * log2(e)
  const f32x4 fzero = {0.f, 0.f, 0.f, 0.f};

#pragma unroll 1
  for (int pass = 0; pass < 2; ++pass) {
    int qt = pass ? p : 31 - p;

    // Q fragments (B operand), 2 row-groups (qi), prescaled by SCALE
    bf16x8 qf[2][2];
#pragma unroll
    for (int qi = 0; qi < 2; ++qi) {
      const __bf16* qp =
          qkv + (size_t)(b * T_SEQ + qt * 64 + w * 32 + qi * 16 + q) * 3072 + h * HD;
      qf[qi][0] = *(const bf16x8*)(qp + g * 8);
      qf[qi][1] = *(const bf16x8*)(qp + 32 + g * 8);
#pragma unroll
      for (int kk = 0; kk < 2; ++kk)
#pragma unroll
        for (int jj = 0; jj < 8; ++jj)
          qf[qi][kk][jj] = (__bf16)((float)qf[qi][kk][jj] * SCALE);
    }

    float m[2] = {-INFINITY, -INFINITY}, lsum[2] = {0.f, 0.f};
    f32x4 yacc[2][4];
#pragma unroll
    for (int qi = 0; qi < 2; ++qi)
#pragma unroll
      for (int f = 0; f < 4; ++f) yacc[qi][f] = fzero;

    // drain Q loads / prior-pass stores so vmcnt accounting is exact
    asm volatile("s_waitcnt vmcnt(0)" ::: "memory");
    __builtin_amdgcn_sched_barrier(0);

    auto STAGE = [&](int kvt, int bi) {
#pragma unroll
      for (int it = 0; it < 4; ++it) {
        int o = it * 2048 + tid * 16;
        int row = o >> 7;
        int ss = ((o >> 4) & 7) ^ (row & 7);
        gload_lds16(qkv + (size_t)(b * T_SEQ + kvt * 64 + row) * 3072 + 1024 + h * HD + ss * 8,
                    (char*)lK[bi] + o);
        gload_lds16(Vt + (size_t)((b * NH + h) * HD + row) * T_SEQ + kvt * 64 + ss * 8,
                    (char*)lV[bi] + o);
      }
    };

    STAGE(0, 0);

#pragma unroll 1
    for (int kvt = 0; kvt <= qt; ++kvt) {
      int cur = kvt & 1;
      if (kvt < qt) {
        STAGE(kvt + 1, cur ^ 1);
        asm volatile("s_waitcnt vmcnt(8)" ::: "memory");  // cur landed; prefetch in flight
      } else {
        asm volatile("s_waitcnt vmcnt(0)" ::: "memory");
      }
      __builtin_amdgcn_sched_barrier(0);
      __builtin_amdgcn_s_barrier();
      __builtin_amdgcn_sched_barrier(0);

      // ---- S^T = K Q^T : s[qi][f][r] = S[qrow(qi,q)][kv = f*16 + g*4 + r] ----
      f32x4 s[2][4];
#pragma unroll
      for (int qi = 0; qi < 2; ++qi)
#pragma unroll
        for (int f = 0; f < 4; ++f) s[qi][f] = fzero;
      const char* Kbase = (const char*)lK[cur];
      __builtin_amdgcn_s_setprio(1);
#pragma unroll
      for (int kk = 0; kk < 2; ++kk)
#pragma unroll
        for (int f = 0; f < 4; ++f) {
          int rk = f * 16 + q;
          int sk = (g + kk * 4) ^ (rk & 7);
          bf16x8 kf = *(const bf16x8*)(Kbase + rk * 128 + sk * 16);
#pragma unroll
          for (int qi = 0; qi < 2; ++qi)
            s[qi][f] = __builtin_amdgcn_mfma_f32_16x16x32_bf16(kf, qf[qi][kk], s[qi][f], 0, 0, 0);
        }
      __builtin_amdgcn_s_setprio(0);

      // ---- causal mask (diagonal tile only) ----
      if (kvt == qt) {
#pragma unroll
        for (int qi = 0; qi < 2; ++qi) {
          int qloc = w * 32 + qi * 16 + q;
#pragma unroll
          for (int f = 0; f < 4; ++f)
#pragma unroll
            for (int r = 0; r < 4; ++r)
              if (f * 16 + g * 4 + r > qloc) s[qi][f][r] = -INFINITY;
        }
      }

      // ---- row max (local tree + 2 shfl) per qi ----
      float mx[2];
#pragma unroll
      for (int qi = 0; qi < 2; ++qi) {
        float v = fmaxf(fmaxf(fmaxf(s[qi][0][0], s[qi][0][1]), fmaxf(s[qi][0][2], s[qi][0][3])),
                        fmaxf(fmaxf(s[qi][1][0], s[qi][1][1]), fmaxf(s[qi][1][2], s[qi][1][3])));
        v = fmaxf(v, fmaxf(fmaxf(fmaxf(s[qi][2][0], s[qi][2][1]), fmaxf(s[qi][2][2], s[qi][2][3])),
                           fmaxf(fmaxf(s[qi][3][0], s[qi][3][1]), fmaxf(s[qi][3][2], s[qi][3][3]))));
        v = fmaxf(v, __shfl_xor(v, 16, 64));
        v = fmaxf(v, __shfl_xor(v, 32, 64));
        mx[qi] = v;
      }

      // ---- defer-max rescale: only when growth exceeds THR=8 (P bounded by 2^8) ----
      float growth = fmaxf(mx[0] - m[0], mx[1] - m[1]);
      if (__any(growth > 8.0f)) {
#pragma unroll
        for (int qi = 0; qi < 2; ++qi) {
          float mn = fmaxf(m[qi], mx[qi]);
          float al = exp2f(m[qi] - mn);
          m[qi] = mn;
          lsum[qi] *= al;
#pragma unroll
          for (int r = 0; r < 4; ++r) {
            float ar = __shfl(al, g * 4 + r, 64);
#pragma unroll
            for (int f = 0; f < 4; ++f) yacc[qi][f][r] *= ar;
          }
        }
      }

      // ---- P = exp2(S - m), packed to bf16 words ----
      unsigned int Wd[2][4][2];
#pragma unroll
      for (int qi = 0; qi < 2; ++qi) {
        float ps = 0.f;
#pragma unroll
        for (int f = 0; f < 4; ++f)
#pragma unroll
          for (int hh = 0; hh < 2; ++hh) {
            float e0 = exp2f(s[qi][f][2 * hh] - m[qi]);
            float e1 = exp2f(s[qi][f][2 * hh + 1] - m[qi]);
            ps += e0 + e1;
            Wd[qi][f][hh] = pack_bf16_2(e0, e1);
          }
        lsum[qi] += ps;
      }

      // ---- redistribute P words into PV A-operand frags ----
      int srcA = ((g & 1) << 5) | q;
      int srcB = srcA + 16;
      bool hisel = (g >= 2);
      bf16x8 pa[2][2];
#pragma unroll
      for (int qi = 0; qi < 2; ++qi)
#pragma unroll
        for (int kk = 0; kk < 2; ++kk) {
          unsigned int pw[4];
#pragma unroll
          for (int t = 0; t < 4; ++t) {
            int src = (t < 2) ? srcA : srcB;
            unsigned int c0 = (unsigned int)__shfl((int)Wd[qi][2 * kk][t & 1], src, 64);
            unsigned int c1 = (unsigned int)__shfl((int)Wd[qi][2 * kk + 1][t & 1], src, 64);
            pw[t] = hisel ? c1 : c0;
          }
          uint4 u = make_uint4(pw[0], pw[1], pw[2], pw[3]);
          pa[qi][kk] = __builtin_bit_cast(bf16x8, u);
        }

      // ---- O += P V ----
      const char* Vbase = (const char*)lV[cur];
      __builtin_amdgcn_s_setprio(1);
#pragma unroll
      for (int kk = 0; kk < 2; ++kk)
#pragma unroll
        for (int f = 0; f < 4; ++f) {
          int rv = f * 16 + q;
          int sv2 = (g + kk * 4) ^ (rv & 7);
          bf16x8 vf = *(const bf16x8*)(Vbase + rv * 128 + sv2 * 16);
#pragma unroll
          for (int qi = 0; qi < 2; ++qi)
            yacc[qi][f] = __builtin_amdgcn_mfma_f32_16x16x32_bf16(pa[qi][kk], vf, yacc[qi][f], 0, 0, 0);
        }
      __builtin_amdgcn_s_setprio(0);

      // all waves done reading cur before next iter's STAGE overwrites the other buffer
      __builtin_amdgcn_sched_barrier(0);
      asm volatile("s_waitcnt lgkmcnt(0)" ::: "memory");
      __builtin_amdgcn_s_barrier();
      __builtin_amdgcn_sched_barrier(0);
    }

    // ---- epilogue ----
#pragma unroll
    for (int qi = 0; qi < 2; ++qi) {
      float ls = lsum[qi];
      ls += __shfl_xor(ls, 16, 64);
      ls += __shfl_xor(ls, 32, 64);
      float linv = 1.0f / ls;
      int qrow = qt * 64 + w * 32 + qi * 16 + g * 4;
#pragma unroll
      for (int r = 0; r < 4; ++r) {
        float lr = __shfl(linv, g * 4 + r, 64);
#pragma unroll
        for (int f = 0; f < 4; ++f) {
          Y[(size_t)(b * T_SEQ + qrow + r) * D_MODEL + h * HD + f * 16 + q] =
              (__bf16)(yacc[qi][f][r] * lr);
        }
      }
    }
  }
}

// ---------------- launcher ----------------
extern "C" void kernel_launch(void* const* d_in, const int* in_sizes, int n_in,
                              void* d_out, int out_size, void* d_ws, size_t ws_size,
                              hipStream_t stream) {
  const float* x = (const float*)d_in[0];      // [4,2048,1024]
  const float* Wqkv = (const float*)d_in[1];   // [1024,3072]
  const float* Wproj = (const float*)d_in[2];  // [1024,1024]
  float* out = (float*)d_out;                  // [4,2048,1024]
  char* ws = (char*)d_ws;

  __bf16* Xbf     = (__bf16*)(ws);                       // 16.78 MB
  __bf16* Wqkv_t  = (__bf16*)(ws + 16777216);            // 6.29 MB  [3072][1024]
  __bf16* Wproj_t = (__bf16*)(ws + 23068672);            // 2.10 MB  [1024][1024]
  __bf16* QKV     = (__bf16*)(ws + 25165824);            // 50.33 MB [8192][3072]
  __bf16* Vt      = (__bf16*)(ws + 75497472);            // 16.78 MB [(b,h,dv)][2048]
  __bf16* Yb      = (__bf16*)(ws + 92274688);            // 16.78 MB [8192][1024]

  cvt_bf16_kernel<<<4096, 256, 0, stream>>>(x, Xbf, NB * T_SEQ * D_MODEL);
  transpose_cvt_kernel<<<dim3(96, 32), dim3(32, 8), 0, stream>>>(Wqkv, Wqkv_t, 1024, 3072);
  transpose_cvt_kernel<<<dim3(32, 32), dim3(32, 8), 0, stream>>>(Wproj, Wproj_t, 1024, 1024);
  gemm_bt<__bf16><<<dim3(24, 64), 256, 0, stream>>>(Xbf, Wqkv_t, QKV, 8192, 3072, 1024);
  extract_vt_kernel<<<dim3(64, 2, 64), dim3(32, 8), 0, stream>>>(QKV, Vt);
  attn_kernel<<<1024, 128, 0, stream>>>(QKV, Vt, Yb);
  gemm_bt<float><<<dim3(8, 64), 256, 0, stream>>>(Yb, Wproj_t, out, 8192, 1024, 1024);
}